// Round 1
// baseline (1424.330 us; speedup 1.0000x reference)
//
#include <hip/hip_runtime.h>
#include <cstdint>
#include <cstddef>

#define B_ 32
#define T_ 2048
#define D_ 128
#define U_ 128
#define G4_ 512
#define P1_ROWS 32

typedef _Float16 h2v __attribute__((ext_vector_type(2)));

__device__ __forceinline__ float dot2f(h2v a, h2v b, float c) {
#if __has_builtin(__builtin_amdgcn_fdot2)
  return __builtin_amdgcn_fdot2(a, b, c, false);
#else
  return c + (float)a[0] * (float)b[0] + (float)a[1] * (float)b[1];
#endif
}

// Phase 1: Zx[t][b][j] = bias[j] + sum_k x[b, tbase+t, k] * Wx[k][j]
// One block = one batch b, 32 consecutive t rows. 512 threads = 512 columns.
__global__ __launch_bounds__(512)
void zx_kernel(const float* __restrict__ x, const float* __restrict__ Wx,
               const float* __restrict__ bias, float* __restrict__ Zx,
               int tbase, int ct) {
  const int j = threadIdx.x;
  const int nt = ct / P1_ROWS;
  const int tblk = blockIdx.x % nt;
  const int b = blockIdx.x / nt;
  const int t0 = tblk * P1_ROWS;

  __shared__ float xsT[D_ * P1_ROWS];  // transposed: [k][r]

  const float* xp = x + ((size_t)b * T_ + tbase + t0) * D_;
  {
    // 32 rows x 128 cols = 4096 floats; each thread stages 8.
    int e = j * 8;
    int r = e >> 7;
    int k = e & 127;
    float4 v0 = *(const float4*)(xp + e);
    float4 v1 = *(const float4*)(xp + e + 4);
    xsT[(k + 0) * P1_ROWS + r] = v0.x;
    xsT[(k + 1) * P1_ROWS + r] = v0.y;
    xsT[(k + 2) * P1_ROWS + r] = v0.z;
    xsT[(k + 3) * P1_ROWS + r] = v0.w;
    xsT[(k + 4) * P1_ROWS + r] = v1.x;
    xsT[(k + 5) * P1_ROWS + r] = v1.y;
    xsT[(k + 6) * P1_ROWS + r] = v1.z;
    xsT[(k + 7) * P1_ROWS + r] = v1.w;
  }
  __syncthreads();

  const float bj = bias[j];
  float acc[P1_ROWS];
#pragma unroll
  for (int r = 0; r < P1_ROWS; ++r) acc[r] = bj;

  const float* wp = Wx + j;
  float w = wp[0];
#pragma unroll 2
  for (int k = 0; k < D_; ++k) {
    float wn = (k + 1 < D_) ? wp[(size_t)(k + 1) * G4_] : 0.f;
    const float4* xr = (const float4*)(xsT + k * P1_ROWS);
#pragma unroll
    for (int r4 = 0; r4 < P1_ROWS / 4; ++r4) {
      float4 xv = xr[r4];
      acc[4 * r4 + 0] += xv.x * w;
      acc[4 * r4 + 1] += xv.y * w;
      acc[4 * r4 + 2] += xv.z * w;
      acc[4 * r4 + 3] += xv.w * w;
    }
    w = wn;
  }

  float* zp = Zx + ((size_t)t0 * B_ + b) * G4_ + j;
#pragma unroll
  for (int r = 0; r < P1_ROWS; ++r)
    zp[(size_t)r * B_ * G4_] = acc[r];
}

// Phase 2: the serial recurrence. One block per batch element (32 blocks).
// Thread j owns z-column j; W_h column j lives in 64 f16x2 VGPRs.
// h lives in LDS as f16 pairs; dot via v_dot2_f32_f16 (f32 accumulate).
__global__ __launch_bounds__(512)
void lstm_kernel(const float* __restrict__ Zx, const float* __restrict__ Wh,
                 float* __restrict__ out, float* __restrict__ state,
                 int tbase, int ct, int first) {
  const int j = threadIdx.x;
  const int b = blockIdx.x;
  const int u = j & (U_ - 1);
  const int gate = j >> 7;  // 0:i 1:f 2:g 3:o (wave-uniform)

  h2v wh[64];
#pragma unroll
  for (int k2 = 0; k2 < 64; ++k2) {
    float w0 = Wh[(size_t)(2 * k2) * G4_ + j];
    float w1 = Wh[(size_t)(2 * k2 + 1) * G4_ + j];
    h2v p;
    p[0] = (_Float16)w0;
    p[1] = (_Float16)w1;
    wh[k2] = p;
  }

  __shared__ h2v hs[64];     // h state as 128 f16 (256 B)
  __shared__ float zs[G4_];  // activated gate exchange (2 KB)

  float creg = 0.f;
  if (j < U_) {
    float h0 = 0.f;
    if (!first) {
      h0 = state[b * 2 * U_ + u];
      creg = state[b * 2 * U_ + U_ + u];
    }
    ((_Float16*)hs)[u] = (_Float16)h0;
  }
  __syncthreads();

  const float* zp = Zx + (size_t)b * G4_ + j;
  float zxc = zp[0];
  float hlast = 0.f;

  for (int t = 0; t < ct; ++t) {
    // prefetch next step's Zx while we compute the dot
    float zxn = (t + 1 < ct) ? zp[(size_t)(t + 1) * B_ * G4_] : 0.f;

    float a0 = 0.f, a1 = 0.f, a2 = 0.f, a3 = 0.f;
    const float4* hs4 = (const float4*)hs;
#pragma unroll
    for (int k8 = 0; k8 < 16; ++k8) {
      float4 hv = hs4[k8];
      a0 = dot2f(__builtin_bit_cast(h2v, hv.x), wh[4 * k8 + 0], a0);
      a1 = dot2f(__builtin_bit_cast(h2v, hv.y), wh[4 * k8 + 1], a1);
      a2 = dot2f(__builtin_bit_cast(h2v, hv.z), wh[4 * k8 + 2], a2);
      a3 = dot2f(__builtin_bit_cast(h2v, hv.w), wh[4 * k8 + 3], a3);
    }
    float z = zxc + ((a0 + a1) + (a2 + a3));

    float act;
    if (gate == 2) {
      // tanh(z) = 2*sigmoid(2z) - 1
      act = 2.f / (1.f + __expf(-2.f * z)) - 1.f;
    } else {
      act = 1.f / (1.f + __expf(-z));
    }
    zs[j] = act;
    __syncthreads();

    if (j < U_) {
      float iv = zs[u];
      float fv = zs[u + 128];
      float gv = zs[u + 256];
      float ov = zs[u + 384];
      creg = iv * gv + fv * creg;
      float tc = 2.f / (1.f + __expf(-2.f * creg)) - 1.f;
      float hn = ov * tc;
      hlast = hn;
      out[((size_t)(tbase + t) * B_ + b) * U_ + u] = hn;
      ((_Float16*)hs)[u] = (_Float16)hn;
    }
    __syncthreads();
    zxc = zxn;
  }

  if (j < U_) {
    state[b * 2 * U_ + u] = hlast;
    state[b * 2 * U_ + U_ + u] = creg;
  }
}

extern "C" void kernel_launch(void* const* d_in, const int* in_sizes, int n_in,
                              void* d_out, int out_size, void* d_ws, size_t ws_size,
                              hipStream_t stream) {
  const float* x = (const float*)d_in[0];
  const float* Wx = (const float*)d_in[1];
  const float* Wh = (const float*)d_in[2];
  const float* bias = (const float*)d_in[3];
  float* out = (float*)d_out;

  // ws layout: [0,32KB) = h/c carry state, rest = Zx chunk buffer
  float* state = (float*)d_ws;
  float* zx = (float*)((char*)d_ws + 32768);
  size_t avail = ws_size > 32768 ? ws_size - 32768 : 0;
  size_t per_t = (size_t)B_ * G4_ * sizeof(float);  // 64 KB per timestep
  long maxct = (long)(avail / per_t);
  int ct;
  if (maxct >= T_) ct = T_;
  else {
    ct = (int)((maxct / P1_ROWS) * P1_ROWS);
    if (ct < P1_ROWS) ct = P1_ROWS;  // assume ws_size is at least ~2 MB
  }

  for (int tb = 0; tb < T_; tb += ct) {
    int cur = (T_ - tb < ct) ? (T_ - tb) : ct;
    zx_kernel<<<dim3(B_ * (cur / P1_ROWS)), 512, 0, stream>>>(x, Wx, bias, zx, tb, cur);
    lstm_kernel<<<dim3(B_), 512, 0, stream>>>(zx, Wh, out, state, tb, cur, tb == 0 ? 1 : 0);
  }
}

// Round 2
// 1239.695 us; speedup vs baseline: 1.1489x; 1.1489x over previous
//
#include <hip/hip_runtime.h>
#include <cstdint>
#include <cstddef>

#define B_ 32
#define T_ 2048
#define D_ 128
#define U_ 128
#define G4_ 512
#define P1_ROWS 32

typedef _Float16 h2v __attribute__((ext_vector_type(2)));

__device__ __forceinline__ float dot2f(h2v a, h2v b, float c) {
#if __has_builtin(__builtin_amdgcn_fdot2)
  return __builtin_amdgcn_fdot2(a, b, c, false);
#else
  return c + (float)a[0] * (float)b[0] + (float)a[1] * (float)b[1];
#endif
}

// quad_perm DPP: XOR1=[1,0,3,2]=0xB1, XOR2=[2,3,0,1]=0x4E, XOR3=[3,2,1,0]=0x1B
template <int CTRL>
__device__ __forceinline__ float qperm(float x) {
  return __builtin_bit_cast(
      float, __builtin_amdgcn_mov_dpp(__builtin_bit_cast(int, x), CTRL, 0xF, 0xF, true));
}
#define XOR1_ 0xB1
#define XOR2_ 0x4E
#define XOR3_ 0x1B

// Packed column for thread/slot j: orig column = (j&3)*128 + (j>>2)
// (gate = j&3, u = j>>2) so the 4 gates of one u live in one quad of lanes.

// Phase 1: Zx[b][j][t] = bias[oc(j)] + sum_k x[b,t,k] * Wx[k][oc(j)]
__global__ __launch_bounds__(512)
void zx_kernel(const float* __restrict__ x, const float* __restrict__ Wx,
               const float* __restrict__ bias, float* __restrict__ Zx,
               int tbase, int ct) {
  const int j = threadIdx.x;
  const int nt = ct / P1_ROWS;
  const int tblk = blockIdx.x % nt;
  const int b = blockIdx.x / nt;
  const int t0 = tblk * P1_ROWS;
  const int oc = (j & 3) * U_ + (j >> 2);  // original (Keras-order) column

  __shared__ float xsT[D_ * P1_ROWS];  // transposed: [k][r]

  const float* xp = x + ((size_t)b * T_ + tbase + t0) * D_;
  {
    int e = j * 8;
    int r = e >> 7;
    int k = e & 127;
    float4 v0 = *(const float4*)(xp + e);
    float4 v1 = *(const float4*)(xp + e + 4);
    xsT[(k + 0) * P1_ROWS + r] = v0.x;
    xsT[(k + 1) * P1_ROWS + r] = v0.y;
    xsT[(k + 2) * P1_ROWS + r] = v0.z;
    xsT[(k + 3) * P1_ROWS + r] = v0.w;
    xsT[(k + 4) * P1_ROWS + r] = v1.x;
    xsT[(k + 5) * P1_ROWS + r] = v1.y;
    xsT[(k + 6) * P1_ROWS + r] = v1.z;
    xsT[(k + 7) * P1_ROWS + r] = v1.w;
  }
  __syncthreads();

  const float bj = bias[oc];
  float acc[P1_ROWS];
#pragma unroll
  for (int r = 0; r < P1_ROWS; ++r) acc[r] = bj;

  const float* wp = Wx + oc;
  float w = wp[0];
#pragma unroll 2
  for (int k = 0; k < D_; ++k) {
    float wn = (k + 1 < D_) ? wp[(size_t)(k + 1) * G4_] : 0.f;
    const float4* xr = (const float4*)(xsT + k * P1_ROWS);
#pragma unroll
    for (int r4 = 0; r4 < P1_ROWS / 4; ++r4) {
      float4 xv = xr[r4];
      acc[4 * r4 + 0] += xv.x * w;
      acc[4 * r4 + 1] += xv.y * w;
      acc[4 * r4 + 2] += xv.z * w;
      acc[4 * r4 + 3] += xv.w * w;
    }
    w = wn;
  }

  float* zp = Zx + ((size_t)b * G4_ + j) * ct + t0;  // [b][col][t], t-contiguous
#pragma unroll
  for (int q = 0; q < P1_ROWS / 4; ++q)
    ((float4*)zp)[q] = make_float4(acc[4 * q], acc[4 * q + 1], acc[4 * q + 2], acc[4 * q + 3]);
}

// Phase 2: serial recurrence, one block per batch element.
// Thread j = (u = j>>2, kq = j&3). Lane kq reads only its 64B k-quarter of h,
// computes partial dots for all 4 gate columns of u, then DPP transpose-reduce
// within the quad. Activation + LSTM cell update via quad DPP exchange.
// One barrier per step, double-buffered h (f16) in LDS.
__global__ __launch_bounds__(512)
void lstm_kernel(const float* __restrict__ Zx, const float* __restrict__ Wh,
                 float* __restrict__ out, float* __restrict__ state,
                 int tbase, int ct, int first) {
  const int j = threadIdx.x;
  const int b = blockIdx.x;
  const int u = j >> 2;
  const int kq = j & 3;
  const bool b0 = (kq & 1) != 0;
  const bool b1 = (kq & 2) != 0;

  // Weights: 4 gate-columns of u, k restricted to quarter kq (32 k = 16 h2v each)
  h2v wh0[16], wh1[16], wh2[16], wh3[16];
#pragma unroll
  for (int k2 = 0; k2 < 16; ++k2) {
    int k0 = kq * 32 + 2 * k2;
    const float* w0p = Wh + (size_t)k0 * G4_;
    const float* w1p = Wh + (size_t)(k0 + 1) * G4_;
    h2v p;
    p[0] = (_Float16)w0p[0 * U_ + u]; p[1] = (_Float16)w1p[0 * U_ + u]; wh0[k2] = p;
    p[0] = (_Float16)w0p[1 * U_ + u]; p[1] = (_Float16)w1p[1 * U_ + u]; wh1[k2] = p;
    p[0] = (_Float16)w0p[2 * U_ + u]; p[1] = (_Float16)w1p[2 * U_ + u]; wh2[k2] = p;
    p[0] = (_Float16)w0p[3 * U_ + u]; p[1] = (_Float16)w1p[3 * U_ + u]; wh3[k2] = p;
  }

  __shared__ h2v hbuf[2][64];  // double-buffered h as 128 f16 each

  float c_state = 0.f, h0 = 0.f;
  if (!first) {
    h0 = state[b * 2 * U_ + u];          // broadcast within quad
    c_state = state[b * 2 * U_ + U_ + u];
  }
  if (kq == 0) ((_Float16*)hbuf[0])[u] = (_Float16)h0;
  __syncthreads();

  const float4* zx4 = (const float4*)(Zx + ((size_t)b * G4_ + j) * ct);
  float4 zcur = zx4[0];
  float hlast = h0;

  for (int tt = 0; tt < ct; tt += 4) {
    float4 znext = (tt + 4 < ct) ? zx4[(tt >> 2) + 1] : make_float4(0.f, 0.f, 0.f, 0.f);
#pragma unroll
    for (int s = 0; s < 4; ++s) {
      const int t = tt + s;
      const float zx_t = (s == 0) ? zcur.x : (s == 1) ? zcur.y : (s == 2) ? zcur.z : zcur.w;
      const int cur = t & 1;

      // read this lane's 64B quarter of h (4 x ds_read_b128, broadcast per 16 lanes)
      const float4* hp = (const float4*)((const char*)hbuf[cur] + kq * 64);
      float p0 = 0.f, p1 = 0.f, p2 = 0.f, p3 = 0.f;
#pragma unroll
      for (int q4 = 0; q4 < 4; ++q4) {
        float4 hv = hp[q4];
        float hw[4] = {hv.x, hv.y, hv.z, hv.w};
#pragma unroll
        for (int e = 0; e < 4; ++e) {
          h2v hh = __builtin_bit_cast(h2v, hw[e]);
          int k2 = q4 * 4 + e;
          p0 = dot2f(hh, wh0[k2], p0);
          p1 = dot2f(hh, wh1[k2], p1);
          p2 = dot2f(hh, wh2[k2], p2);
          p3 = dot2f(hh, wh3[k2], p3);
        }
      }

      // quad transpose-reduce: lane kq ends with full dot for gate-column kq
      float sx = b0 ? p0 : p1;
      float sy = b0 ? p2 : p3;
      float rx = qperm<XOR1_>(sx);
      float ry = qperm<XOR1_>(sy);
      float e0 = (b0 ? p1 : p0) + rx;   // col (kq&1) over half the k-range
      float e1 = (b0 ? p3 : p2) + ry;   // col 2+(kq&1)
      float sz = b1 ? e0 : e1;
      float rz = qperm<XOR2_>(sz);
      float z = (b1 ? e1 : e0) + rz + zx_t;  // full z for gate kq of u

      // activation: sigmoid for i,f,o; tanh for g (gate 2)
      const bool isg = (kq == 2);
      float zz = isg ? z + z : z;
      float ex = __expf(-zz);
      float sg = __builtin_amdgcn_rcpf(1.f + ex);
      float act = isg ? 2.f * sg - 1.f : sg;

      // quad all-gather of gate activations via DPP
      float X1 = qperm<XOR1_>(act);
      float X2 = qperm<XOR2_>(act);
      float X3 = qperm<XOR3_>(act);
      // i = X[kq], f = X[kq^1], g = X[kq^2], o = X[kq^3]  (X0 == act)
      float ig = (b0 ? X1 : act) * (b0 ? X3 : X2);          // i*g, same on all lanes
      float f_ = b0 ? (b1 ? X2 : act) : (b1 ? X3 : X1);
      float o_ = b0 ? (b1 ? act : X2) : (b1 ? X1 : X3);

      c_state = fmaf(f_, c_state, ig);
      float e2 = __expf(-2.f * c_state);
      float th = 2.f * __builtin_amdgcn_rcpf(1.f + e2) - 1.f;
      float hn = o_ * th;
      hlast = hn;

      if (kq == 0) {
        out[((size_t)(tbase + t) * B_ + b) * U_ + u] = hn;
        ((_Float16*)hbuf[cur ^ 1])[u] = (_Float16)hn;
      }
      __syncthreads();  // next-step h visible; one barrier per step
    }
    zcur = znext;
  }

  if (kq == 0) {
    state[b * 2 * U_ + u] = hlast;
    state[b * 2 * U_ + U_ + u] = c_state;
  }
}

extern "C" void kernel_launch(void* const* d_in, const int* in_sizes, int n_in,
                              void* d_out, int out_size, void* d_ws, size_t ws_size,
                              hipStream_t stream) {
  const float* x = (const float*)d_in[0];
  const float* Wx = (const float*)d_in[1];
  const float* Wh = (const float*)d_in[2];
  const float* bias = (const float*)d_in[3];
  float* out = (float*)d_out;

  // ws layout: [0,32KB) = h/c carry state, rest = Zx chunk buffer
  float* state = (float*)d_ws;
  float* zx = (float*)((char*)d_ws + 32768);
  size_t avail = ws_size > 32768 ? ws_size - 32768 : 0;
  size_t per_t = (size_t)B_ * G4_ * sizeof(float);  // 64 KB per timestep
  long maxct = (long)(avail / per_t);
  int ct;
  if (maxct >= T_) ct = T_;
  else {
    ct = (int)((maxct / P1_ROWS) * P1_ROWS);
    if (ct < P1_ROWS) ct = P1_ROWS;
  }

  for (int tb = 0; tb < T_; tb += ct) {
    int cur = (T_ - tb < ct) ? (T_ - tb) : ct;
    zx_kernel<<<dim3(B_ * (cur / P1_ROWS)), 512, 0, stream>>>(x, Wx, bias, zx, tb, cur);
    lstm_kernel<<<dim3(B_), 512, 0, stream>>>(zx, Wh, out, state, tb, cur, tb == 0 ? 1 : 0);
  }
}

// Round 3
// 1196.312 us; speedup vs baseline: 1.1906x; 1.0363x over previous
//
#include <hip/hip_runtime.h>
#include <cstdint>
#include <cstddef>

#define B_ 32
#define T_ 2048
#define D_ 128
#define U_ 128
#define G4_ 512
#define P1_ROWS 32

typedef _Float16 f16x8 __attribute__((ext_vector_type(8)));
typedef float f32x4 __attribute__((ext_vector_type(4)));

__device__ __forceinline__ float sigf(float z) {
  return __builtin_amdgcn_rcpf(1.f + __expf(-z));
}
__device__ __forceinline__ float tanhf_(float z) {
  return 2.f * __builtin_amdgcn_rcpf(1.f + __expf(-2.f * z)) - 1.f;
}

// Phase 1: Zx[b][col][t] = bias[col] + sum_k x[b,t,k] * Wx[k][col]
__global__ __launch_bounds__(512)
void zx_kernel(const float* __restrict__ x, const float* __restrict__ Wx,
               const float* __restrict__ bias, float* __restrict__ Zx,
               int tbase, int ct) {
  const int j = threadIdx.x;
  const int nt = ct / P1_ROWS;
  const int tblk = blockIdx.x % nt;
  const int b = blockIdx.x / nt;
  const int t0 = tblk * P1_ROWS;

  __shared__ float xsT[D_ * P1_ROWS];  // transposed: [k][r]

  const float* xp = x + ((size_t)b * T_ + tbase + t0) * D_;
  {
    int e = j * 8;
    int r = e >> 7;
    int k = e & 127;
    float4 v0 = *(const float4*)(xp + e);
    float4 v1 = *(const float4*)(xp + e + 4);
    xsT[(k + 0) * P1_ROWS + r] = v0.x;
    xsT[(k + 1) * P1_ROWS + r] = v0.y;
    xsT[(k + 2) * P1_ROWS + r] = v0.z;
    xsT[(k + 3) * P1_ROWS + r] = v0.w;
    xsT[(k + 4) * P1_ROWS + r] = v1.x;
    xsT[(k + 5) * P1_ROWS + r] = v1.y;
    xsT[(k + 6) * P1_ROWS + r] = v1.z;
    xsT[(k + 7) * P1_ROWS + r] = v1.w;
  }
  __syncthreads();

  const float bj = bias[j];
  float acc[P1_ROWS];
#pragma unroll
  for (int r = 0; r < P1_ROWS; ++r) acc[r] = bj;

  const float* wp = Wx + j;
  float w = wp[0];
#pragma unroll 2
  for (int k = 0; k < D_; ++k) {
    float wn = (k + 1 < D_) ? wp[(size_t)(k + 1) * G4_] : 0.f;
    const float4* xr = (const float4*)(xsT + k * P1_ROWS);
#pragma unroll
    for (int r4 = 0; r4 < P1_ROWS / 4; ++r4) {
      float4 xv = xr[r4];
      acc[4 * r4 + 0] += xv.x * w;
      acc[4 * r4 + 1] += xv.y * w;
      acc[4 * r4 + 2] += xv.z * w;
      acc[4 * r4 + 3] += xv.w * w;
    }
    w = wn;
  }

  float* zp = Zx + ((size_t)b * G4_ + j) * ct + t0;  // [b][col][t], t-contiguous
#pragma unroll
  for (int q = 0; q < P1_ROWS / 4; ++q)
    ((float4*)zp)[q] = make_float4(acc[4 * q], acc[4 * q + 1], acc[4 * q + 2], acc[4 * q + 3]);
}

// Phase 2: serial recurrence via f16 MFMA. One block (8 waves) per batch.
// Wave w owns u in [16w, 16w+16); its 4 N-tiles are the 4 gates of those u.
// A-frag = h broadcast (all 16 rows identical) -> any C row is z.
// Lane (col = lane&15) holds i,f,g,o of its u in acc0..acc3 -> lane-local cell.
__global__ __launch_bounds__(512)
void lstm_kernel(const float* __restrict__ Zx, const float* __restrict__ Wh,
                 float* __restrict__ out, float* __restrict__ state,
                 int tbase, int ct, int first) {
  const int j = threadIdx.x;
  const int b = blockIdx.x;
  const int w = j >> 6;
  const int lane = j & 63;
  const int l4 = lane & 15;
  const int kg = lane >> 4;       // k-group 0..3
  const int u = w * 16 + l4;      // duplicated across kg groups

  // B fragments: Wh[k][col], col = g*128+u, k = kt*32 + kg*8 + e (f32 -> f16)
  f16x8 bf[4][4];
#pragma unroll
  for (int g = 0; g < 4; ++g)
#pragma unroll
    for (int kt = 0; kt < 4; ++kt) {
      f16x8 v;
#pragma unroll
      for (int e = 0; e < 8; ++e)
        v[e] = (_Float16)Wh[(size_t)(kt * 32 + kg * 8 + e) * G4_ + g * U_ + u];
      bf[g][kt] = v;
    }

  __shared__ alignas(16) _Float16 hbuf[2][U_];  // double-buffered h (f16)

  float c_state = 0.f, h0 = 0.f;
  if (!first) {
    h0 = state[b * 2 * U_ + u];
    c_state = state[b * 2 * U_ + U_ + u];
  }
  if (kg == 0) hbuf[0][u] = (_Float16)h0;
  __syncthreads();

  const float4* zq0 = (const float4*)(Zx + ((size_t)b * G4_ + 0 * U_ + u) * ct);
  const float4* zq1 = (const float4*)(Zx + ((size_t)b * G4_ + 1 * U_ + u) * ct);
  const float4* zq2 = (const float4*)(Zx + ((size_t)b * G4_ + 2 * U_ + u) * ct);
  const float4* zq3 = (const float4*)(Zx + ((size_t)b * G4_ + 3 * U_ + u) * ct);

  float4 zc0 = zq0[0], zc1 = zq1[0], zc2 = zq2[0], zc3 = zq3[0];
  float hlast = h0;

  for (int tt = 0; tt < ct; tt += 4) {
    float4 zn0, zn1, zn2, zn3;
    if (tt + 4 < ct) {
      const int nq = (tt >> 2) + 1;
      zn0 = zq0[nq]; zn1 = zq1[nq]; zn2 = zq2[nq]; zn3 = zq3[nq];
    } else {
      zn0 = zn1 = zn2 = zn3 = make_float4(0.f, 0.f, 0.f, 0.f);
    }
#pragma unroll
    for (int s = 0; s < 4; ++s) {
      const int t = tt + s;
      const int cur = t & 1;
      const float zi0 = (s == 0) ? zc0.x : (s == 1) ? zc0.y : (s == 2) ? zc0.z : zc0.w;
      const float zi1 = (s == 0) ? zc1.x : (s == 1) ? zc1.y : (s == 2) ? zc1.z : zc1.w;
      const float zi2 = (s == 0) ? zc2.x : (s == 1) ? zc2.y : (s == 2) ? zc2.z : zc2.w;
      const float zi3 = (s == 0) ? zc3.x : (s == 1) ? zc3.y : (s == 2) ? zc3.z : zc3.w;

      // A-frags: broadcast h slice per k-group (16B per kt)
      const f16x8* hp = (const f16x8*)hbuf[cur];
      f16x8 a0 = hp[0 * 4 + kg];
      f16x8 a1 = hp[1 * 4 + kg];
      f16x8 a2 = hp[2 * 4 + kg];
      f16x8 a3 = hp[3 * 4 + kg];

      f32x4 acc0 = {zi0, zi0, zi0, zi0};
      f32x4 acc1 = {zi1, zi1, zi1, zi1};
      f32x4 acc2 = {zi2, zi2, zi2, zi2};
      f32x4 acc3 = {zi3, zi3, zi3, zi3};
      // kt-outer ordering interleaves the 4 independent chains
      acc0 = __builtin_amdgcn_mfma_f32_16x16x32_f16(a0, bf[0][0], acc0, 0, 0, 0);
      acc1 = __builtin_amdgcn_mfma_f32_16x16x32_f16(a0, bf[1][0], acc1, 0, 0, 0);
      acc2 = __builtin_amdgcn_mfma_f32_16x16x32_f16(a0, bf[2][0], acc2, 0, 0, 0);
      acc3 = __builtin_amdgcn_mfma_f32_16x16x32_f16(a0, bf[3][0], acc3, 0, 0, 0);
      acc0 = __builtin_amdgcn_mfma_f32_16x16x32_f16(a1, bf[0][1], acc0, 0, 0, 0);
      acc1 = __builtin_amdgcn_mfma_f32_16x16x32_f16(a1, bf[1][1], acc1, 0, 0, 0);
      acc2 = __builtin_amdgcn_mfma_f32_16x16x32_f16(a1, bf[2][1], acc2, 0, 0, 0);
      acc3 = __builtin_amdgcn_mfma_f32_16x16x32_f16(a1, bf[3][1], acc3, 0, 0, 0);
      acc0 = __builtin_amdgcn_mfma_f32_16x16x32_f16(a2, bf[0][2], acc0, 0, 0, 0);
      acc1 = __builtin_amdgcn_mfma_f32_16x16x32_f16(a2, bf[1][2], acc1, 0, 0, 0);
      acc2 = __builtin_amdgcn_mfma_f32_16x16x32_f16(a2, bf[2][2], acc2, 0, 0, 0);
      acc3 = __builtin_amdgcn_mfma_f32_16x16x32_f16(a2, bf[3][2], acc3, 0, 0, 0);
      acc0 = __builtin_amdgcn_mfma_f32_16x16x32_f16(a3, bf[0][3], acc0, 0, 0, 0);
      acc1 = __builtin_amdgcn_mfma_f32_16x16x32_f16(a3, bf[1][3], acc1, 0, 0, 0);
      acc2 = __builtin_amdgcn_mfma_f32_16x16x32_f16(a3, bf[2][3], acc2, 0, 0, 0);
      acc3 = __builtin_amdgcn_mfma_f32_16x16x32_f16(a3, bf[3][3], acc3, 0, 0, 0);

      float i_ = sigf(acc0[0]);
      float f_ = sigf(acc1[0]);
      float g_ = tanhf_(acc2[0]);
      float o_ = sigf(acc3[0]);
      c_state = fmaf(f_, c_state, i_ * g_);
      float hn = o_ * tanhf_(c_state);
      hlast = hn;

      if (kg == 0) {
        out[((size_t)(tbase + t) * B_ + b) * U_ + u] = hn;
        hbuf[cur ^ 1][u] = (_Float16)hn;
      }
      __syncthreads();
    }
    zc0 = zn0; zc1 = zn1; zc2 = zn2; zc3 = zn3;
  }

  if (kg == 0) {
    state[b * 2 * U_ + u] = hlast;
    state[b * 2 * U_ + U_ + u] = c_state;
  }
}

extern "C" void kernel_launch(void* const* d_in, const int* in_sizes, int n_in,
                              void* d_out, int out_size, void* d_ws, size_t ws_size,
                              hipStream_t stream) {
  const float* x = (const float*)d_in[0];
  const float* Wx = (const float*)d_in[1];
  const float* Wh = (const float*)d_in[2];
  const float* bias = (const float*)d_in[3];
  float* out = (float*)d_out;

  // ws layout: [0,32KB) = h/c carry state, rest = Zx chunk buffer
  float* state = (float*)d_ws;
  float* zx = (float*)((char*)d_ws + 32768);
  size_t avail = ws_size > 32768 ? ws_size - 32768 : 0;
  size_t per_t = (size_t)B_ * G4_ * sizeof(float);  // 64 KB per timestep
  long maxct = (long)(avail / per_t);
  int ct;
  if (maxct >= T_) ct = T_;
  else {
    ct = (int)((maxct / P1_ROWS) * P1_ROWS);
    if (ct < P1_ROWS) ct = P1_ROWS;
  }

  for (int tb = 0; tb < T_; tb += ct) {
    int cur = (T_ - tb < ct) ? (T_ - tb) : ct;
    zx_kernel<<<dim3(B_ * (cur / P1_ROWS)), 512, 0, stream>>>(x, Wx, bias, zx, tb, cur);
    lstm_kernel<<<dim3(B_), 512, 0, stream>>>(zx, Wh, out, state, tb, cur, tb == 0 ? 1 : 0);
  }
}